// Round 13
// baseline (20.176 us; speedup 1.0000x reference)
//
#include <hip/hip_runtime.h>

// Bidirectional Chamfer distance, fp32, (16, 2048, 3) — dual-orientation MFMA.
//
// R13: compute BOTH D (A=pred,B=tgt) and D^T (A=tgt,B=pred) so that each
// direction's min is LANE-LOCAL (fold over the 16 acc regs), eliminating
// R11/R12's per-tile cross-lane shuffles + colpart LDS round-trip (the
// inferred ~6 us LDS-pipe epilogue). MFMAs double (512/block) but MFMA is
// ~0.4 us/CU — cross-lane ops were the cost, not matrix math.
//
// Packing (R11-verified slot layout, v = coordinate triple, s = |v|^2):
//   A-pack(v,s): a0=[h0,h1,h2, l0,l1,l2, h0,h1]  a1=[h2, l0,l1,l2, s_h,s_l, 1,1]
//   B-pack(v,s): b0=[h0,h1,h2, h0,h1,h2, l0,l1]  b1=[l2, l0,l1,l2, 1,1, s_h,s_l]
//   D   = mfma(Apack(-2p, pp), Bpack(t, tt))  -> d2[i][j], lane = tgt col
//   D^T = mfma(Apack(-2t, tt), Bpack(p, pp))  -> d2[j][i], lane = pred col
//
// chamfer: 256 blocks = batch(16) x pred-strip(16 of 128 rows), 512 thr =
//   8 waves. Wave w owns tgt tiles [w*8, w*8+8) in both orientations:
//   Loop1: 8 tgt-col-tiles x 4 pred-row-tiles -> tmin[8] (tgt-min partial)
//   Loop2: 8 tgt-row-tiles x 4 pred-col-tiles -> pmin[4] (pred-min partial)
//   End: shfl_xor(32) g-combine (12 ops), tmin -> wscol, pmin -> 4KB LDS
//   rowpart -> cross-wave min + sum -> wsrow. LDS 140 KB, 1 block/CU.
// reduce: R12's verbatim (64 blocks, coalesced, 64 atomics).

typedef __attribute__((ext_vector_type(8)))  short s16x8;
typedef __attribute__((ext_vector_type(16))) float f32x16;

#define NPTS   2048
#define BATCH  16
#define MSTRIP 128
#define NSTRIP 16
#define NBLK   256
#define SCALE  (1.0f / 32768.0f)

__device__ __forceinline__ unsigned short bf16_rne(float f) {
    unsigned int u = __float_as_uint(f);
    return (unsigned short)((u + 0x7fffu + ((u >> 16) & 1u)) >> 16);
}
__device__ __forceinline__ float bf16_up(unsigned short h) {
    return __uint_as_float(((unsigned int)h) << 16);
}
__device__ __forceinline__ void split(float v, unsigned short& hi, unsigned short& lo) {
    hi = bf16_rne(v);
    lo = bf16_rne(v - bf16_up(hi));
}

#define ONEBF ((short)0x3f80)

// Build A-pack halves from splits (h0..h2, l0..l2) and scalar split (sh, sl).
__device__ __forceinline__ void mkA(s16x8& a0, s16x8& a1,
    unsigned short h0, unsigned short h1, unsigned short h2,
    unsigned short l0, unsigned short l1, unsigned short l2,
    unsigned short sh, unsigned short sl)
{
    a0[0]=(short)h0; a0[1]=(short)h1; a0[2]=(short)h2; a0[3]=(short)l0;
    a0[4]=(short)l1; a0[5]=(short)l2; a0[6]=(short)h0; a0[7]=(short)h1;
    a1[0]=(short)h2; a1[1]=(short)l0; a1[2]=(short)l1; a1[3]=(short)l2;
    a1[4]=(short)sh; a1[5]=(short)sl; a1[6]=ONEBF;     a1[7]=ONEBF;
}
__device__ __forceinline__ void mkB(s16x8& b0, s16x8& b1,
    unsigned short h0, unsigned short h1, unsigned short h2,
    unsigned short l0, unsigned short l1, unsigned short l2,
    unsigned short sh, unsigned short sl)
{
    b0[0]=(short)h0; b0[1]=(short)h1; b0[2]=(short)h2; b0[3]=(short)h0;
    b0[4]=(short)h1; b0[5]=(short)h2; b0[6]=(short)l0; b0[7]=(short)l1;
    b1[0]=(short)l2; b1[1]=(short)l0; b1[2]=(short)l1; b1[3]=(short)l2;
    b1[4]=ONEBF;     b1[5]=ONEBF;     b1[6]=(short)sh; b1[7]=(short)sl;
}

__device__ __forceinline__ float fold16(f32x16 a) {
    const float c0 = fminf(a[0], a[1]),   c1 = fminf(a[2], a[3]);
    const float c2 = fminf(a[4], a[5]),   c3 = fminf(a[6], a[7]);
    const float c4 = fminf(a[8], a[9]),   c5 = fminf(a[10], a[11]);
    const float c6 = fminf(a[12], a[13]), c7 = fminf(a[14], a[15]);
    return fminf(fminf(fminf(c0, c1), fminf(c2, c3)),
                 fminf(fminf(c4, c5), fminf(c6, c7)));
}

__global__ __launch_bounds__(512, 2) void chamfer_kernel(
    const float* __restrict__ pred,
    const float* __restrict__ tgt,
    float* __restrict__ wscol,     // [NBLK][NPTS] tgt-min partials
    float* __restrict__ wsrow,     // [NBLK] pred-min rowsum
    float* __restrict__ out)
{
    const int bid   = blockIdx.x;
    const int b     = bid >> 4;
    const int strip = bid & 15;
    const int tid   = threadIdx.x;
    const int w  = tid >> 6, l = tid & 63;
    const int cl = l & 31, g = l >> 5;

    if (bid == 0 && tid == 0) out[0] = 0.0f;   // read only by reduce node

    const float* Pb = pred + (size_t)b * NPTS * 3;
    const float* Tb = tgt  + (size_t)b * NPTS * 3;

    __shared__ s16x8 bfrB[NPTS * 2];   // 64 KB tgt B-packs (plain t, tt)
    __shared__ s16x8 bfrA[NPTS * 2];   // 64 KB tgt A-packs (-2t, tt)
    __shared__ s16x8 pfrA[MSTRIP * 2]; // 4 KB pred A-packs (-2p, pp)
    __shared__ s16x8 pfrB[MSTRIP * 2]; // 4 KB pred B-packs (plain p, pp)
    __shared__ float rowpart[8][MSTRIP]; // 4 KB
    __shared__ float rsum_s[2];

    // --- Stage tgt: 4 points per thread, both packings ---
    {
        const float4* T4 = (const float4*)Tb;
        const float4 va = T4[tid * 3 + 0];
        const float4 vb = T4[tid * 3 + 1];
        const float4 vc = T4[tid * 3 + 2];
        const float xs[4] = {va.x, va.w, vb.z, vc.y};
        const float ys[4] = {va.y, vb.x, vb.w, vc.z};
        const float zs[4] = {va.z, vb.y, vc.x, vc.w};
        #pragma unroll
        for (int k = 0; k < 4; ++k) {
            const int c = tid * 4 + k;
            const float x = xs[k], y = ys[k], z = zs[k];
            unsigned short hx, lx, hy, ly, hz, lz;          // plain t
            unsigned short shx, slx, shy, sly, shz, slz;    // -2t
            unsigned short th, tl;                          // tt
            split(x, hx, lx); split(y, hy, ly); split(z, hz, lz);
            split(-2.0f * x, shx, slx); split(-2.0f * y, shy, sly);
            split(-2.0f * z, shz, slz);
            split(x * x + y * y + z * z, th, tl);
            s16x8 b0, b1, a0, a1;
            mkB(b0, b1, hx, hy, hz, lx, ly, lz, th, tl);
            mkA(a0, a1, shx, shy, shz, slx, sly, slz, th, tl);
            const int base = (c >> 5) * 64 + (c & 31);
            bfrB[base] = b0; bfrB[base + 32] = b1;
            bfrA[base] = a0; bfrA[base + 32] = a1;
        }
    }

    // --- Stage pred strip: threads 0..127, one point each, both packings ---
    if (tid < MSTRIP) {
        const int c = tid;
        const int grow = strip * MSTRIP + c;
        const float x = Pb[grow * 3 + 0];
        const float y = Pb[grow * 3 + 1];
        const float z = Pb[grow * 3 + 2];
        unsigned short hx, lx, hy, ly, hz, lz;
        unsigned short shx, slx, shy, sly, shz, slz;
        unsigned short ph, pl;
        split(x, hx, lx); split(y, hy, ly); split(z, hz, lz);
        split(-2.0f * x, shx, slx); split(-2.0f * y, shy, sly);
        split(-2.0f * z, shz, slz);
        split(x * x + y * y + z * z, ph, pl);
        s16x8 a0, a1, b0, b1;
        mkA(a0, a1, shx, shy, shz, slx, sly, slz, ph, pl);
        mkB(b0, b1, hx, hy, hz, lx, ly, lz, ph, pl);
        const int base = (c >> 5) * 64 + (c & 31);
        pfrA[base] = a0; pfrA[base + 32] = a1;
        pfrB[base] = b0; pfrB[base + 32] = b1;
    }

    __syncthreads();

    // --- Register fragments: pred rows (A for D), pred cols (B for D^T) ---
    s16x8 af[4], bp[4];
    #pragma unroll
    for (int rt = 0; rt < 4; ++rt) af[rt] = pfrA[rt * 64 + l];
    #pragma unroll
    for (int pc = 0; pc < 4; ++pc) bp[pc] = pfrB[pc * 64 + l];

    f32x16 zacc;
    #pragma unroll
    for (int r = 0; r < 16; ++r) zacc[r] = 0.0f;

    float tmin[8], pmin[4];
    #pragma unroll
    for (int t = 0; t < 8; ++t) tmin[t] = 3.4e38f;
    #pragma unroll
    for (int t = 0; t < 4; ++t) pmin[t] = 3.4e38f;

    // --- Loop1: D = pred-rows x tgt-cols -> tgt-min (lane = tgt col) ---
    #pragma unroll 2
    for (int ct = 0; ct < 8; ++ct) {
        const s16x8 bf = bfrB[(w * 8 + ct) * 64 + l];
        #pragma unroll
        for (int rt = 0; rt < 4; ++rt) {
            const f32x16 acc =
                __builtin_amdgcn_mfma_f32_32x32x16_bf16(af[rt], bf, zacc, 0, 0, 0);
            tmin[ct] = fminf(tmin[ct], fold16(acc));
        }
    }

    // --- Loop2: D^T = tgt-rows x pred-cols -> pred-min (lane = pred col) ---
    #pragma unroll 2
    for (int rt2 = 0; rt2 < 8; ++rt2) {
        const s16x8 at = bfrA[(w * 8 + rt2) * 64 + l];
        #pragma unroll
        for (int pc = 0; pc < 4; ++pc) {
            const f32x16 acc =
                __builtin_amdgcn_mfma_f32_32x32x16_bf16(at, bp[pc], zacc, 0, 0, 0);
            pmin[pc] = fminf(pmin[pc], fold16(acc));
        }
    }

    // --- Combine g-halves (rows 16..31 of each tile live in lanes 32..63) ---
    #pragma unroll
    for (int ct = 0; ct < 8; ++ct)
        tmin[ct] = fminf(tmin[ct], __shfl_xor(tmin[ct], 32));
    #pragma unroll
    for (int pc = 0; pc < 4; ++pc)
        pmin[pc] = fminf(pmin[pc], __shfl_xor(pmin[pc], 32));

    if (g == 0) {
        #pragma unroll
        for (int ct = 0; ct < 8; ++ct)
            wscol[(size_t)bid * NPTS + w * 256 + ct * 32 + cl] = tmin[ct];
        #pragma unroll
        for (int pc = 0; pc < 4; ++pc)
            rowpart[w][pc * 32 + cl] = pmin[pc];
    }
    __syncthreads();

    // --- rowsum: min over 8 waves per pred row, sum 128 rows ---
    if (tid < MSTRIP) {
        float v = rowpart[0][tid];
        #pragma unroll
        for (int ww = 1; ww < 8; ++ww)
            v = fminf(v, rowpart[ww][tid]);
        #pragma unroll
        for (int off = 32; off > 0; off >>= 1)
            v += __shfl_down(v, off);
        if ((tid & 63) == 0) rsum_s[tid >> 6] = v;
    }
    __syncthreads();
    if (tid == 0) wsrow[bid] = rsum_s[0] + rsum_s[1];
}

// reduce: 64 blocks = batch(16) x col-chunk(4 of 512 cols). Coalesced
// float4 reads: min over 16 strips, sum over 512 cols, plus 4 rowsum
// entries, ONE scaled atomicAdd into out[0] (64 atomics total).
__global__ __launch_bounds__(128) void reduce_kernel(
    const float* __restrict__ wscol,
    const float* __restrict__ wsrow,
    float* __restrict__ out)
{
    const int g    = blockIdx.x;       // 0..63
    const int bb   = g >> 2;           // batch
    const int cc   = g & 3;            // col-chunk of 512
    const int tid  = threadIdx.x;      // 0..127
    const int lane = tid & 63;
    __shared__ float s2[2];

    const float4* base = (const float4*)(wscol + (size_t)bb * NSTRIP * NPTS
                                               + (size_t)cc * 512);
    float4 m = base[tid];
    #pragma unroll
    for (int s = 1; s < 16; ++s) {
        const float4 v = base[(size_t)s * (NPTS / 4) + tid];
        m.x = fminf(m.x, v.x); m.y = fminf(m.y, v.y);
        m.z = fminf(m.z, v.z); m.w = fminf(m.w, v.w);
    }
    float acc = (m.x + m.y) + (m.z + m.w);

    #pragma unroll
    for (int off = 32; off > 0; off >>= 1)
        acc += __shfl_down(acc, off);
    if (lane == 0) s2[tid >> 6] = acc;
    __syncthreads();

    if (tid == 0) {
        const float rs = (wsrow[4 * g + 0] + wsrow[4 * g + 1])
                       + (wsrow[4 * g + 2] + wsrow[4 * g + 3]);
        atomicAdd(out, ((s2[0] + s2[1]) + rs) * SCALE);
    }
}

extern "C" void kernel_launch(void* const* d_in, const int* in_sizes, int n_in,
                              void* d_out, int out_size, void* d_ws, size_t ws_size,
                              hipStream_t stream)
{
    const float* pred = (const float*)d_in[0];
    const float* tgt  = (const float*)d_in[1];
    float* out   = (float*)d_out;
    float* wscol = (float*)d_ws;                             // 2 MB
    float* wsrow = (float*)d_ws + (size_t)NBLK * NPTS;       // 256 floats

    chamfer_kernel<<<dim3(NBLK), dim3(512), 0, stream>>>(pred, tgt, wscol, wsrow, out);
    reduce_kernel<<<dim3(64), dim3(128), 0, stream>>>(wscol, wsrow, out);
}